// Round 3
// baseline (3910.479 us; speedup 1.0000x reference)
//
#include <hip/hip_runtime.h>
#include <hip/hip_bf16.h>

typedef __bf16 bf16x8 __attribute__((ext_vector_type(8)));
typedef float f32x4 __attribute__((ext_vector_type(4)));

__device__ __forceinline__ unsigned short f2bf(float f) {
    unsigned int u = __builtin_bit_cast(unsigned int, f);
    u += 0x7FFFu + ((u >> 16) & 1u);
    return (unsigned short)(u >> 16);
}
__device__ __forceinline__ float bf2f(unsigned short s) {
    unsigned int u = ((unsigned int)s) << 16;
    return __builtin_bit_cast(float, u);
}

// ---------------- prep: x -> split bf16 hi/lo in MFMA B-fragment layout ----------------
// layout: [t(200)][nt(8)][kc(16)][lane(64)][e(8)]; batch = nt*16+(lane&15), k = kc*32+(lane>>4)*8+e
__global__ void prep_x(const float* __restrict__ x,
                       unsigned short* __restrict__ xh,
                       unsigned short* __restrict__ xl) {
    int g = blockIdx.x * 256 + threadIdx.x;   // frag index, 1,638,400 total
    if (g >= 1638400) return;
    int lane = g & 63;
    int kc   = (g >> 6) & 15;
    int nt   = (g >> 10) & 7;
    int t    = g >> 13;
    int batch = nt * 16 + (lane & 15);
    int k = kc * 32 + (lane >> 4) * 8;
    const float* s = x + ((size_t)batch * 200 + t) * 512 + k;
    float4 v0 = *(const float4*)s;
    float4 v1 = *(const float4*)(s + 4);
    float vv[8] = {v0.x, v0.y, v0.z, v0.w, v1.x, v1.y, v1.z, v1.w};
    unsigned int ph[4], pl[4];
    #pragma unroll
    for (int j = 0; j < 4; ++j) {
        float a = vv[2*j], b = vv[2*j+1];
        unsigned short ha = f2bf(a), hb = f2bf(b);
        unsigned short la = f2bf(a - bf2f(ha)), lb = f2bf(b - bf2f(hb));
        ph[j] = (unsigned)ha | ((unsigned)hb << 16);
        pl[j] = (unsigned)la | ((unsigned)lb << 16);
    }
    ((uint4*)xh)[g] = make_uint4(ph[0], ph[1], ph[2], ph[3]);
    ((uint4*)xl)[g] = make_uint4(pl[0], pl[1], pl[2], pl[3]);
}

// ---------------- prep: weights -> split hi/lo in MFMA A-fragment layout ----------------
// src: [L=2][2048][512] fp32.  dst: [wsel=dir*2+l][rt(128)][kc(16)][lane(64)][e(8)]
// row = rt*16+(lane&15), k = kc*32+(lane>>4)*8+e
__global__ void prep_w(const float* __restrict__ W,
                       unsigned short* __restrict__ wh,
                       unsigned short* __restrict__ wl, int dir) {
    int g = blockIdx.x * 256 + threadIdx.x;   // 262,144 frags
    if (g >= 262144) return;
    int lane = g & 63;
    int kc   = (g >> 6) & 15;
    int rt   = (g >> 10) & 127;
    int l    = g >> 17;
    int row = rt * 16 + (lane & 15);
    int k = kc * 32 + (lane >> 4) * 8;
    const float* s = W + ((size_t)l * 2048 + row) * 512 + k;
    float4 v0 = *(const float4*)s;
    float4 v1 = *(const float4*)(s + 4);
    float vv[8] = {v0.x, v0.y, v0.z, v0.w, v1.x, v1.y, v1.z, v1.w};
    unsigned int ph[4], pl[4];
    #pragma unroll
    for (int j = 0; j < 4; ++j) {
        float a = vv[2*j], b = vv[2*j+1];
        unsigned short ha = f2bf(a), hb = f2bf(b);
        unsigned short la = f2bf(a - bf2f(ha)), lb = f2bf(b - bf2f(hb));
        ph[j] = (unsigned)ha | ((unsigned)hb << 16);
        pl[j] = (unsigned)la | ((unsigned)lb << 16);
    }
    size_t d = (size_t)(dir * 2 + l) * 131072 + (size_t)((rt * 16 + kc) * 64 + lane);
    ((uint4*)wh)[d] = make_uint4(ph[0], ph[1], ph[2], ph[3]);
    ((uint4*)wl)[d] = make_uint4(pl[0], pl[1], pl[2], pl[3]);
}

__global__ void bsum_k(const float* __restrict__ bih_f, const float* __restrict__ bhh_f,
                       const float* __restrict__ bih_b, const float* __restrict__ bhh_b,
                       float* __restrict__ bsum) {
    int i = blockIdx.x * 256 + threadIdx.x;   // 8192 = [dir][l][2048]
    if (i < 8192) {
        int dir = i >> 12, rem = i & 4095;
        const float* bi = dir ? bih_b : bih_f;
        const float* bh = dir ? bhh_b : bhh_f;
        bsum[i] = bi[rem] + bh[rem];
    }
}

__global__ void reset_k(uint4* __restrict__ p) {  // zero h_hi | h_lo | c  (3,145,728 B)
    int g = blockIdx.x * 256 + threadIdx.x;
    if (g < 196608) p[g] = make_uint4(0, 0, 0, 0);
}

// ---------------- pipelined LSTM step ----------------
// launch tau: slot0 = layer0 @ t0=tau, slot1 = layer1 @ t1=tau-1.
// role decode keeps each XCD on one (slot,dir) and an rg-half -> 4MB weight set per XCD L2.
// WG: 128 gate rows (32 hidden units of rg) x 32 batches (nh quarter).
// 4 waves K-split (kh): each does kc = kh*4..kh*4+3; partial gates exchanged via LDS.
__launch_bounds__(256, 1)
__global__ void lstm_step(
    const unsigned short* __restrict__ xh,
    const unsigned short* __restrict__ xl,
    const unsigned short* __restrict__ wihh,
    const unsigned short* __restrict__ wihl,
    const unsigned short* __restrict__ whhh,
    const unsigned short* __restrict__ whhl,
    const float*          __restrict__ bsum,
    unsigned short*       __restrict__ h_hi,   // [layer][parity][dir] x 65536 (frag layout)
    unsigned short*       __restrict__ h_lo,
    float*                __restrict__ cst,    // [layer][dir][512][128]
    const int*            __restrict__ lens,   // int32! (JAX x64-disabled downcasts int64)
    float*                __restrict__ dout,   // [128][200][1024]
    int t0, int t1)
{
    __shared__ float glds[4][128][32];

    int wg  = blockIdx.x;
    int xcd = wg & 7, i = wg >> 3;            // i: 0..31
    int sd  = xcd >> 1;                       // 0..3
    int slot = sd >> 1, dir = sd & 1;
    int rg  = ((xcd & 1) << 3) | (i >> 2);    // 0..15
    int nh  = i & 3;                          // 0..3

    int t = slot ? t1 : t0;
    if (t < 0 || t > 199) return;
    int t_eff = dir ? (199 - t) : t;
    int wsel = dir * 2 + slot;

    int tid = threadIdx.x;
    int lane = tid & 63, kh = tid >> 6;
    int p_r = t & 1, p_w = 1 - p_r;

    const unsigned short* AihH = wihh + ((size_t)wsel << 20);
    const unsigned short* AihL = wihl + ((size_t)wsel << 20);
    const unsigned short* AhhH = whhh + ((size_t)wsel << 20);
    const unsigned short* AhhL = whhl + ((size_t)wsel << 20);
    const unsigned short* HrdH = h_hi + ((size_t)((slot * 2 + p_r) * 2 + dir) << 16);
    const unsigned short* HrdL = h_lo + ((size_t)((slot * 2 + p_r) * 2 + dir) << 16);
    unsigned short* HwrH = h_hi + ((size_t)((slot * 2 + p_w) * 2 + dir) << 16);
    unsigned short* HwrL = h_lo + ((size_t)((slot * 2 + p_w) * 2 + dir) << 16);
    float* Cs = cst + ((size_t)(slot * 2 + dir) << 16);

    const unsigned short* XH;
    const unsigned short* XL;
    bool mval0, mval1;
    if (slot == 0) {
        XH = xh + (size_t)t_eff * 65536;
        XL = xl + (size_t)t_eff * 65536;
        mval0 = mval1 = true;
    } else {
        int p_x = 1 - (t & 1);                 // layer0 wrote h_t here at launch tau-1
        XH = h_hi + ((size_t)(p_x * 2 + dir) << 16);
        XL = h_lo + ((size_t)(p_x * 2 + dir) << 16);
        mval0 = t_eff < lens[(nh * 2 + 0) * 16 + (lane & 15)];
        mval1 = t_eff < lens[(nh * 2 + 1) * 16 + (lane & 15)];
    }

    f32x4 acc[8][2];
    #pragma unroll
    for (int mt = 0; mt < 8; ++mt)
        #pragma unroll
        for (int nt = 0; nt < 2; ++nt)
            acc[mt][nt] = (f32x4){0.f, 0.f, 0.f, 0.f};

    size_t lofs = (size_t)kh * 2048 + (size_t)lane * 8;

    #pragma unroll
    for (int kcl = 0; kcl < 4; ++kcl) {
        bf16x8 bxh[2], bxl[2], bhh_f_[2], bhl_f_[2];
        #pragma unroll
        for (int nt = 0; nt < 2; ++nt) {
            size_t bo = (size_t)(nh * 2 + nt) * 8192 + lofs + (size_t)kcl * 512;
            uint4 vh = *(const uint4*)(XH + bo);
            uint4 vl = *(const uint4*)(XL + bo);
            bool mv = nt ? mval1 : mval0;
            if (!mv) { vh = make_uint4(0,0,0,0); vl = make_uint4(0,0,0,0); }
            bxh[nt] = __builtin_bit_cast(bf16x8, vh);
            bxl[nt] = __builtin_bit_cast(bf16x8, vl);
            bhh_f_[nt] = *(const bf16x8*)(HrdH + bo);
            bhl_f_[nt] = *(const bf16x8*)(HrdL + bo);
        }
        #pragma unroll
        for (int mt = 0; mt < 8; ++mt) {
            int rt = (mt >> 1) * 32 + rg * 2 + (mt & 1);   // rowtile of gate (mt>>1), unit-half (mt&1)
            size_t ao = (size_t)rt * 8192 + lofs + (size_t)kcl * 512;
            bf16x8 aih = *(const bf16x8*)(AihH + ao);
            bf16x8 ail = *(const bf16x8*)(AihL + ao);
            bf16x8 ahh = *(const bf16x8*)(AhhH + ao);
            bf16x8 ahl = *(const bf16x8*)(AhhL + ao);
            #pragma unroll
            for (int nt = 0; nt < 2; ++nt) {
                f32x4 a = acc[mt][nt];
                a = __builtin_amdgcn_mfma_f32_16x16x32_bf16(aih, bxh[nt],   a, 0, 0, 0);
                a = __builtin_amdgcn_mfma_f32_16x16x32_bf16(aih, bxl[nt],   a, 0, 0, 0);
                a = __builtin_amdgcn_mfma_f32_16x16x32_bf16(ail, bxh[nt],   a, 0, 0, 0);
                a = __builtin_amdgcn_mfma_f32_16x16x32_bf16(ahh, bhh_f_[nt], a, 0, 0, 0);
                a = __builtin_amdgcn_mfma_f32_16x16x32_bf16(ahh, bhl_f_[nt], a, 0, 0, 0);
                a = __builtin_amdgcn_mfma_f32_16x16x32_bf16(ahl, bhh_f_[nt], a, 0, 0, 0);
                acc[mt][nt] = a;
            }
        }
    }

    // partial-gate exchange (XOR bit4 of col with row parity to dodge bank conflicts)
    int crow = (lane >> 4) * 4, col = lane & 15;
    #pragma unroll
    for (int mt = 0; mt < 8; ++mt)
        #pragma unroll
        for (int nt = 0; nt < 2; ++nt)
            #pragma unroll
            for (int r = 0; r < 4; ++r) {
                int rr = mt * 16 + crow + r;
                glds[kh][rr][(nt * 16 + col) ^ ((rr & 1) << 4)] = acc[mt][nt][r];
            }
    __syncthreads();

    // cell update: 32 hidden x 32 batches = 1024 items
    #pragma unroll
    for (int it = 0; it < 4; ++it) {
        int item = tid + it * 256;
        int b = item & 31, u = item >> 5;
        float g[4];
        #pragma unroll
        for (int q = 0; q < 4; ++q) {
            int rr = q * 32 + u;
            int cc = b ^ ((rr & 1) << 4);
            g[q] = glds[0][rr][cc] + glds[1][rr][cc] + glds[2][rr][cc] + glds[3][rr][cc]
                 + bsum[wsel * 2048 + q * 512 + rg * 32 + u];
        }
        int gb = nh * 32 + b;          // global batch
        int hj = rg * 32 + u;          // global hidden unit
        float cv = Cs[hj * 128 + gb];
        float iG = 1.f / (1.f + expf(-g[0]));
        float fG = 1.f / (1.f + expf(-g[1]));
        float gG = tanhf(g[2]);
        float oG = 1.f / (1.f + expf(-g[3]));
        float cn = fG * cv + iG * gG;
        Cs[hj * 128 + gb] = cn;
        float hn = oG * tanhf(cn);
        unsigned short hhi_ = f2bf(hn);
        unsigned short hlo_ = f2bf(hn - bf2f(hhi_));
        size_t ho = (((size_t)(gb >> 4) * 16 + (hj >> 5)) * 64
                     + (((hj >> 3) & 3) * 16 + (gb & 15))) * 8 + (hj & 7);
        HwrH[ho] = hhi_;
        HwrL[ho] = hlo_;
        if (slot) {
            float hm = (t_eff < lens[gb]) ? hn : 0.f;
            dout[((size_t)gb * 200 + t_eff) * 1024 + dir * 512 + hj] = hm;
        }
    }
}

// ---------------- host ----------------
extern "C" void kernel_launch(void* const* d_in, const int* in_sizes, int n_in,
                              void* d_out, int out_size, void* d_ws, size_t ws_size,
                              hipStream_t stream) {
    const float* x     = (const float*)d_in[0];
    const int*   lens  = (const int*)d_in[1];     // int32 per harness convention
    const float* Wih_f = (const float*)d_in[2];
    const float* Whh_f = (const float*)d_in[3];
    const float* bih_f = (const float*)d_in[4];
    const float* bhh_f = (const float*)d_in[5];
    const float* Wih_b = (const float*)d_in[6];
    const float* Whh_b = (const float*)d_in[7];
    const float* bih_b = (const float*)d_in[8];
    const float* bhh_b = (const float*)d_in[9];
    float* out = (float*)d_out;
    char* ws = (char*)d_ws;
    if (ws_size < 89161728) return;

    unsigned short* xh   = (unsigned short*)(ws);                 // 26,214,400
    unsigned short* xl   = (unsigned short*)(ws + 26214400);      // 26,214,400
    unsigned short* wihh = (unsigned short*)(ws + 52428800);      //  8,388,608
    unsigned short* wihl = (unsigned short*)(ws + 60817408);      //  8,388,608
    unsigned short* whhh = (unsigned short*)(ws + 69206016);      //  8,388,608
    unsigned short* whhl = (unsigned short*)(ws + 77594624);      //  8,388,608
    float*          bsum = (float*)(ws + 85983232);               //     32,768
    unsigned short* hhi  = (unsigned short*)(ws + 86016000);      //  1,048,576
    unsigned short* hlo  = (unsigned short*)(ws + 87064576);      //  1,048,576
    float*          cst  = (float*)(ws + 88113152);               //  1,048,576

    prep_x<<<6400, 256, 0, stream>>>(x, xh, xl);
    prep_w<<<1024, 256, 0, stream>>>(Wih_f, wihh, wihl, 0);
    prep_w<<<1024, 256, 0, stream>>>(Wih_b, wihh, wihl, 1);
    prep_w<<<1024, 256, 0, stream>>>(Whh_f, whhh, whhl, 0);
    prep_w<<<1024, 256, 0, stream>>>(Whh_b, whhh, whhl, 1);
    bsum_k<<<32, 256, 0, stream>>>(bih_f, bhh_f, bih_b, bhh_b, bsum);
    reset_k<<<768, 256, 0, stream>>>((uint4*)hhi);   // zeroes hhi | hlo | cst (contiguous)

    for (int tau = 0; tau <= 200; ++tau)
        lstm_step<<<256, 256, 0, stream>>>(xh, xl, wihh, wihl, whhh, whhl,
                                           bsum, hhi, hlo, cst, lens, out, tau, tau - 1);
}